// Round 8
// baseline (1734.402 us; speedup 1.0000x reference)
//
#include <hip/hip_runtime.h>

typedef __bf16 bf16_t;
typedef bf16_t bf16x8 __attribute__((ext_vector_type(8)));
typedef float  f32x4  __attribute__((ext_vector_type(4)));

#define MFMA16(A, B, C) __builtin_amdgcn_mfma_f32_16x16x32_bf16((A), (B), (C), 0, 0, 0)

static constexpr int KEXT   = 288;  // 256 h | 3 x | 1 ones(bias) | 28 zero pad
static constexpr int HS     = 296;  // LDS row stride (592 B: 16B-aligned, ~2-way bank alias)
static constexpr int TSTEPS = 128;
static constexpr int TILE_B = 16;   // 256 blocks x 512 thr -> 1 block/CU

// ws layout (bf16 elements)
static constexpr int WALL_OFF = 0;                    // [1152][288] gates(1024) + Wo1ext(128)
static constexpr int W2E_OFF  = 1152 * 288;           // [512][288]  encoder layer2 (+b2 col)
static constexpr int WO2E_OFF = W2E_OFF + 512 * 288;  // [16][128]   Wo2 padded
static constexpr int WS_ELEMS = WO2E_OFF + 16 * 128;

// ---------------- prep: pack weights bf16 (ws re-poisoned every launch) ----------------
__global__ __launch_bounds__(256) void prep_kernel(
    const float* __restrict__ W2,  const float* __restrict__ b2,
    const float* __restrict__ Wih, const float* __restrict__ Whh,
    const float* __restrict__ bih, const float* __restrict__ bhh,
    const float* __restrict__ Wo1, const float* __restrict__ bo1,
    const float* __restrict__ Wo2, bf16_t* __restrict__ ws)
{
    int idx = blockIdx.x * 256 + threadIdx.x;
    if (idx < 1152 * 288) {
        int r = idx / 288, k = idx - r * 288;
        float v = 0.f;
        if (r < 1024) {                       // gate rows: i f g o (256 each)
            if (k < 256)       v = Whh[r * 256 + k];
            else if (k < 259)  v = Wih[r * 3 + (k - 256)];
            else if (k == 259) v = bih[r] + bhh[r];
        } else {                              // Wo1 rows (zeros at x cols, bo1 at ones col)
            int q = r - 1024;
            if (k < 256)       v = Wo1[q * 256 + k];
            else if (k == 259) v = bo1[q];
        }
        ws[WALL_OFF + idx] = (bf16_t)v;
    } else if (idx < W2E_OFF + 512 * 288) {
        int j = idx - W2E_OFF;
        int u = j / 288, k = j - u * 288;
        float v = 0.f;
        if (k < 256)       v = W2[u * 256 + k];
        else if (k == 259) v = b2[u];
        ws[idx] = (bf16_t)v;
    } else if (idx < WS_ELEMS) {
        int j = idx - WO2E_OFF;
        int d = j >> 7, q = j & 127;
        ws[idx] = (bf16_t)((d < 3) ? Wo2[d * 128 + q] : 0.f);
    }
}

__device__ __forceinline__ float sigm(float x) { return 1.f / (1.f + __expf(-x)); }
__device__ __forceinline__ float tanh_f(float x) {
    float a = fminf(fmaxf(x, -15.f), 15.f);
    float e = __expf(2.f * a);
    return (e - 1.f) / (e + 1.f);
}
__device__ __forceinline__ unsigned pk2(float a, float b) {
    union { bf16_t h[2]; unsigned u; } x;
    x.h[0] = (bf16_t)a; x.h[1] = (bf16_t)b; return x.u;
}

// ---------------- main: 256 blocks x 512 thr (8 waves); block owns 16 batches.
// Round-8 changes vs R7: 2 barriers/step (x_{t+1} carried in regs via redundant
// y-MFMA in all waves); y accumulated in LDS, flushed once (no per-step
// partial-line RMW to fabric); next-step k-tile prefetched across phase 4;
// per-block k-rotation decorrelates the 32 blocks/XCD on the weight stream.
__global__ __launch_bounds__(512) void lstm_main(
    const float* __restrict__ meta, const float* __restrict__ W1,
    const float* __restrict__ b1,   const float* __restrict__ bo2,
    const bf16_t* __restrict__ ws,  float* __restrict__ out)
{
    __shared__ __align__(16) bf16_t hx[2][TILE_B][HS];  // h (cols 0..255; 256+ junk-read-ok)
    __shared__ __align__(16) bf16_t wo1l[128][HS];      // Wo1ext; aliased as cbuf fp32 in setup
    __shared__ __align__(16) bf16_t wo2l[16][136];
    __shared__ __align__(16) bf16_t zbuf[TILE_B][136];
    __shared__            float  ybuf[TILE_B][392];     // y accumulation, flushed at end

    const int tid  = threadIdx.x;
    const int wv   = tid >> 6;       // 0..7
    const int lane = tid & 63;
    const int l15  = lane & 15;
    const int quad = lane >> 4;      // 0..3
    const int gb   = blockIdx.x * TILE_B;
    const int kofs = blockIdx.x % 9; // per-block k-rotation

    const bf16_t* wall = ws + WALL_OFF;
    const bf16_t* w2e  = ws + W2E_OFF;
    const bf16_t* wo2e = ws + WO2E_OFF;
    const f32x4 zero4 = {0.f, 0.f, 0.f, 0.f};

    const float b20 = bo2[0], b21 = bo2[1], b22 = bo2[2];

    // zero-frag and "ones-only" frag (col 259 = 1.0 in quad 0, j=3)
    union fu { bf16x8 v; unsigned u[4]; };
    fu zf; zf.u[0] = 0; zf.u[1] = 0; zf.u[2] = 0; zf.u[3] = 0;
    fu onef = zf; onef.u[1] = pk2(0.f, 1.f);
    const bf16x8 bfe = (quad == 0) ? onef.v : zf.v;

    // x-feedback fragment: quad0 lane l15 holds {x0,x1,x2,1,0,0,0,0} of batch l15
    bf16x8 bfx;
    {
        fu x0; x0 = zf;
        float m0 = meta[(size_t)(gb + l15) * 7 + 0];
        float m1 = meta[(size_t)(gb + l15) * 7 + 1];
        float m2 = meta[(size_t)(gb + l15) * 7 + 2];
        x0.u[0] = pk2(m0, m1); x0.u[1] = pk2(m2, 1.f);
        bfx = (quad == 0) ? x0.v : zf.v;
    }

    // ---- enc1 (VALU, K=7) into hx[1] ----
    {
        int b = tid & 15, j0 = (tid >> 4) * 8;
        float m[7];
        #pragma unroll
        for (int k = 0; k < 7; ++k) m[k] = meta[(size_t)(gb + b) * 7 + k];
        #pragma unroll
        for (int jj = 0; jj < 8; ++jj) {
            int jd = j0 + jj;
            float acc = b1[jd];
            #pragma unroll
            for (int k = 0; k < 7; ++k) acc += W1[jd * 7 + k] * m[k];
            hx[1][b][jd] = (bf16_t)fmaxf(acc, 0.f);
        }
    }
    __syncthreads();

    // ---- enc2 via MFMA: wave wv rows [64wv,64wv+64); rows<256 -> h0(hx[0]), >=256 -> c0(cbuf) ----
    float* cbuf = (float*)&wo1l[0][0];  // fp32 [256][17]
    {
        f32x4 e[4] = {zero4, zero4, zero4, zero4};
        #pragma unroll
        for (int kk = 0; kk < 9; ++kk) {
            int ko = 32 * kk + 8 * quad;
            bf16x8 bf = (kk == 8) ? bfe : *(const bf16x8*)&hx[1][l15][ko];
            #pragma unroll
            for (int m = 0; m < 4; ++m) {
                bf16x8 a = *(const bf16x8*)&w2e[(size_t)(64 * wv + 16 * m + l15) * KEXT + ko];
                e[m] = MFMA16(a, bf, e[m]);
            }
        }
        #pragma unroll
        for (int m = 0; m < 4; ++m) {
            int row = 64 * wv + 16 * m + 4 * quad;
            if (row < 256) {  // h0
                *(unsigned*)&hx[0][l15][row]     = pk2(fmaxf(e[m][0], 0.f), fmaxf(e[m][1], 0.f));
                *(unsigned*)&hx[0][l15][row + 2] = pk2(fmaxf(e[m][2], 0.f), fmaxf(e[m][3], 0.f));
            } else {          // c0
                int d = row - 256;
                #pragma unroll
                for (int r = 0; r < 4; ++r)
                    cbuf[(size_t)(d + r) * 17 + l15] = fmaxf(e[m][r], 0.f);
            }
        }
    }
    __syncthreads();

    // ---- c0 -> regs: c[half][r] at dim 32wv+16half+4quad+r, batch l15 ----
    f32x4 c[2];
    #pragma unroll
    for (int half = 0; half < 2; ++half)
        #pragma unroll
        for (int r = 0; r < 4; ++r)
            c[half][r] = cbuf[(size_t)(32 * wv + 16 * half + 4 * quad + r) * 17 + l15];
    __syncthreads();

    // ---- Wo1 -> LDS (overwrites cbuf); Wo2 -> LDS ----
    #pragma unroll
    for (int i = 0; i < 9; ++i) {
        int idx = tid + 512 * i;
        int r = idx / 36, c8 = idx - r * 36;
        *(bf16x8*)&wo1l[r][8 * c8] = *(const bf16x8*)&wall[(size_t)(1024 + r) * KEXT + 8 * c8];
    }
    #pragma unroll
    for (int i = 0; i < 4; ++i) {
        int idx = tid + 512 * i;
        int r = idx >> 7, cc = idx & 127;
        wo2l[r][cc] = wo2e[r * 128 + cc];
    }

    // streamed gate rows: row-tile rt (gate g=rt>>1, half h=rt&1)
    const bf16_t* sb = wall + (size_t)(32 * wv + l15) * KEXT + 8 * quad;
    auto PF = [&](int kk, bf16x8* dst) {
        #pragma unroll
        for (int rt = 0; rt < 8; ++rt) {
            int g = rt >> 1, h = rt & 1;
            dst[rt] = *(const bf16x8*)(sb + (size_t)(256 * g + 16 * h) * KEXT + 32 * kk);
        }
    };

    bf16x8 frA[8], frB[8];
    PF(kofs, frA);                 // first k-tile in flight before the loop
    __syncthreads();               // wo1l/wo2l visible

    // ================= time loop (2 barriers/step) =================
    for (int t = 0; t < TSTEPS; ++t) {
        const bf16_t (*cur)[HS] = hx[t & 1];
        bf16_t (*nxt)[HS]       = hx[(t + 1) & 1];

        // -- phase 1: gates; k-tiles visited in rotated order; ping-pong prefetch --
        f32x4 acc[8];
        #pragma unroll
        for (int rt = 0; rt < 8; ++rt) acc[rt] = zero4;

        #pragma unroll
        for (int i = 0; i < 9; ++i) {
            int kk = kofs + i; if (kk >= 9) kk -= 9;
            bf16x8 ldsv = *(const bf16x8*)&cur[l15][32 * kk + 8 * quad];
            bf16x8 bf   = (kk == 8) ? bfx : ldsv;
            if (i < 8) {
                int kn = kofs + i + 1; if (kn >= 9) kn -= 9;
                PF(kn, (i & 1) ? frA : frB);
            }
            const bf16x8* src = (i & 1) ? frB : frA;
            #pragma unroll
            for (int rt = 0; rt < 8; ++rt)
                acc[rt] = MFMA16(src[rt], bf, acc[rt]);
        }

        // -- phase 2: cell update (regs) + write h_{t+1} --
        #pragma unroll
        for (int half = 0; half < 2; ++half) {
            float hh[4];
            #pragma unroll
            for (int r = 0; r < 4; ++r) {
                float iv = acc[0 + half][r], fv = acc[2 + half][r];
                float gv = acc[4 + half][r], ov = acc[6 + half][r];
                float cc = sigm(fv) * c[half][r] + sigm(iv) * tanh_f(gv);
                c[half][r] = cc;
                hh[r] = sigm(ov) * tanh_f(cc);
            }
            int dim = 32 * wv + 16 * half + 4 * quad;
            *(unsigned*)&nxt[l15][dim]     = pk2(hh[0], hh[1]);
            *(unsigned*)&nxt[l15][dim + 2] = pk2(hh[2], hh[3]);
        }
        __syncthreads();   // B1: h_{t+1} complete

        // -- phase 3: z = relu(h_{t+1} @ Wo1^T + bo1); wave wv -> z-dims [16wv,16wv+16) --
        {
            f32x4 za = zero4;
            #pragma unroll
            for (int kk = 0; kk < 9; ++kk) {
                int ko = 32 * kk + 8 * quad;
                bf16x8 a = *(const bf16x8*)&wo1l[16 * wv + l15][ko];
                bf16x8 b = (kk == 8) ? bfx : *(const bf16x8*)&nxt[l15][ko]; // x cols x 0; ones->bo1
                za = MFMA16(a, b, za);
            }
            int zd = 16 * wv + 4 * quad;
            *(unsigned*)&zbuf[l15][zd]     = pk2(fmaxf(za[0], 0.f), fmaxf(za[1], 0.f));
            *(unsigned*)&zbuf[l15][zd + 2] = pk2(fmaxf(za[2], 0.f), fmaxf(za[3], 0.f));
        }
        __syncthreads();   // B2: z complete

        // -- phase 4 (ALL waves, redundant): prefetch next k-tile; y = z @ Wo2^T + bo2 --
        PF(kofs, frA);     // next step's first k-tile: in flight across phase 4 (no barrier between)
        {
            f32x4 ya = zero4;
            #pragma unroll
            for (int kk = 0; kk < 4; ++kk) {
                int ko = 32 * kk + 8 * quad;
                ya = MFMA16(*(const bf16x8*)&wo2l[l15][ko],
                            *(const bf16x8*)&zbuf[l15][ko], ya);
            }
            float y0 = ya[0] + b20, y1 = ya[1] + b21, y2 = ya[2] + b22;
            fu nb; nb = zf; nb.u[0] = pk2(y0, y1); nb.u[1] = pk2(y2, 1.f);
            bfx = (quad == 0) ? nb.v : zf.v;        // x_{t+1} carried in regs -> no 3rd barrier
            if (wv == 0 && quad == 0) {
                ybuf[l15][3 * t + 0] = y0;
                ybuf[l15][3 * t + 1] = y1;
                ybuf[l15][3 * t + 2] = y2;
            }
        }
    }

    // ---- flush y to global once, full-line vectorized ----
    __syncthreads();
    {
        int b = tid >> 5, j = tid & 31;       // 16 batches x 32 threads x 12 floats
        float* op = out + (size_t)(gb + b) * 384 + 12 * j;
        #pragma unroll
        for (int k2 = 0; k2 < 3; ++k2) {
            float4 v;
            v.x = ybuf[b][12 * j + 4 * k2 + 0];
            v.y = ybuf[b][12 * j + 4 * k2 + 1];
            v.z = ybuf[b][12 * j + 4 * k2 + 2];
            v.w = ybuf[b][12 * j + 4 * k2 + 3];
            *(float4*)(op + 4 * k2) = v;
        }
    }
}

extern "C" void kernel_launch(void* const* d_in, const int* in_sizes, int n_in,
                              void* d_out, int out_size, void* d_ws, size_t ws_size,
                              hipStream_t stream)
{
    const float* meta = (const float*)d_in[0];
    const float* W1   = (const float*)d_in[2];
    const float* b1   = (const float*)d_in[3];
    const float* W2   = (const float*)d_in[4];
    const float* b2   = (const float*)d_in[5];
    const float* Wih  = (const float*)d_in[6];
    const float* Whh  = (const float*)d_in[7];
    const float* bih  = (const float*)d_in[8];
    const float* bhh  = (const float*)d_in[9];
    const float* Wo1  = (const float*)d_in[10];
    const float* bo1  = (const float*)d_in[11];
    const float* Wo2  = (const float*)d_in[12];
    const float* bo2  = (const float*)d_in[13];
    bf16_t* ws  = (bf16_t*)d_ws;
    float*  out = (float*)d_out;

    prep_kernel<<<dim3((WS_ELEMS + 255) / 256), dim3(256), 0, stream>>>(
        W2, b2, Wih, Whh, bih, bhh, Wo1, bo1, Wo2, ws);
    lstm_main<<<dim3(4096 / TILE_B), dim3(512), 0, stream>>>(
        meta, W1, b1, bo2, ws, out);
}

// Round 9
// 1639.533 us; speedup vs baseline: 1.0579x; 1.0579x over previous
//
#include <hip/hip_runtime.h>

typedef __bf16 bf16_t;
typedef bf16_t bf16x8 __attribute__((ext_vector_type(8)));
typedef float  f32x4  __attribute__((ext_vector_type(4)));

#define MFMA16(A, B, C) __builtin_amdgcn_mfma_f32_16x16x32_bf16((A), (B), (C), 0, 0, 0)

static constexpr int KEXT   = 288;  // 256 h | 3 x | 1 ones(bias) | 28 zero pad
static constexpr int HS     = 296;  // LDS row stride (592 B: 16B-aligned, ~2-way bank alias)
static constexpr int TSTEPS = 128;
static constexpr int TILE_B = 16;   // 256 blocks x 1024 thr -> 1 block/CU, 16 waves/CU

// ws layout (bf16 elements)
static constexpr int WALL_OFF = 0;                    // [1152][288] gates(1024) + Wo1ext(128)
static constexpr int W2E_OFF  = 1152 * 288;           // [512][288]  encoder layer2 (+b2 col)
static constexpr int WO2E_OFF = W2E_OFF + 512 * 288;  // [16][128]   Wo2 padded
static constexpr int WS_ELEMS = WO2E_OFF + 16 * 128;

// ---------------- prep: pack weights bf16 (ws re-poisoned every launch) ----------------
__global__ __launch_bounds__(256) void prep_kernel(
    const float* __restrict__ W2,  const float* __restrict__ b2,
    const float* __restrict__ Wih, const float* __restrict__ Whh,
    const float* __restrict__ bih, const float* __restrict__ bhh,
    const float* __restrict__ Wo1, const float* __restrict__ bo1,
    const float* __restrict__ Wo2, bf16_t* __restrict__ ws)
{
    int idx = blockIdx.x * 256 + threadIdx.x;
    if (idx < 1152 * 288) {
        int r = idx / 288, k = idx - r * 288;
        float v = 0.f;
        if (r < 1024) {                       // gate rows: i f g o (256 each)
            if (k < 256)       v = Whh[r * 256 + k];
            else if (k < 259)  v = Wih[r * 3 + (k - 256)];
            else if (k == 259) v = bih[r] + bhh[r];
        } else {                              // Wo1 rows (zeros at x cols, bo1 at ones col)
            int q = r - 1024;
            if (k < 256)       v = Wo1[q * 256 + k];
            else if (k == 259) v = bo1[q];
        }
        ws[WALL_OFF + idx] = (bf16_t)v;
    } else if (idx < W2E_OFF + 512 * 288) {
        int j = idx - W2E_OFF;
        int u = j / 288, k = j - u * 288;
        float v = 0.f;
        if (k < 256)       v = W2[u * 256 + k];
        else if (k == 259) v = b2[u];
        ws[idx] = (bf16_t)v;
    } else if (idx < WS_ELEMS) {
        int j = idx - WO2E_OFF;
        int d = j >> 7, q = j & 127;
        ws[idx] = (bf16_t)((d < 3) ? Wo2[d * 128 + q] : 0.f);
    }
}

__device__ __forceinline__ float sigm(float x) { return 1.f / (1.f + __expf(-x)); }
__device__ __forceinline__ float tanh_f(float x) {
    float a = fminf(fmaxf(x, -15.f), 15.f);
    float e = __expf(2.f * a);
    return (e - 1.f) / (e + 1.f);
}
__device__ __forceinline__ unsigned pk2(float a, float b) {
    union { bf16_t h[2]; unsigned u; } x;
    x.h[0] = (bf16_t)a; x.h[1] = (bf16_t)b; return x.u;
}

// ---------------- main: 256 blocks x 1024 thr (16 waves); block owns 16 batches.
// R9 vs R7: same 3-barrier structure, same stream, but 16 waves (4/SIMD, 2x TLP)
// with per-wave state sized to the 64-VGPR budget at 1024 thr:
// acc[4] (16) + fr[4] (16) + c (4) + bf (4) + addr/misc (~20) ~= 60. NO SPILL.
// Wave wv: gate dims [16wv,16wv+16) x 4 gates x 16 batches.
__global__ __launch_bounds__(1024) void lstm_main(
    const float* __restrict__ meta, const float* __restrict__ W1,
    const float* __restrict__ b1,   const float* __restrict__ bo2,
    const bf16_t* __restrict__ ws,  float* __restrict__ out)
{
    __shared__ __align__(16) bf16_t hx[2][TILE_B][HS];  // [h(256)|x(3)|1|pad] double-buffered
    __shared__ __align__(16) bf16_t wo1l[128][HS];      // Wo1ext; aliased as cbuf fp32 in setup
    __shared__ __align__(16) bf16_t wo2l[16][136];
    __shared__ __align__(16) bf16_t zbuf[TILE_B][136];

    const int tid  = threadIdx.x;
    const int wv   = tid >> 6;       // 0..15
    const int lane = tid & 63;
    const int l15  = lane & 15;
    const int quad = lane >> 4;      // 0..3
    const int gb   = blockIdx.x * TILE_B;

    const bf16_t* wall = ws + WALL_OFF;
    const bf16_t* w2e  = ws + W2E_OFF;
    const bf16_t* wo2e = ws + WO2E_OFF;
    const f32x4 zero4 = {0.f, 0.f, 0.f, 0.f};

    // ---- init ext cols of both hx buffers (x0 in buf0; ones col; zero pad) ----
    if (tid < 32) {
        int buf = tid >> 4, b = tid & 15;
        for (int c = 256; c < HS; ++c) {
            float v = 0.f;
            if (c < 259)       v = buf ? 0.f : meta[(size_t)(gb + b) * 7 + (c - 256)];
            else if (c == 259) v = 1.f;
            hx[buf][b][c] = (bf16_t)v;
        }
    }
    // ---- enc1 (VALU, K=7) into hx[1]: thread -> batch tid&15, dims 4*(tid>>4) ----
    {
        int b = tid & 15, j0 = (tid >> 4) * 4;
        float m[7];
        #pragma unroll
        for (int k = 0; k < 7; ++k) m[k] = meta[(size_t)(gb + b) * 7 + k];
        #pragma unroll
        for (int jj = 0; jj < 4; ++jj) {
            int jd = j0 + jj;
            float acc = b1[jd];
            #pragma unroll
            for (int k = 0; k < 7; ++k) acc += W1[jd * 7 + k] * m[k];
            hx[1][b][jd] = (bf16_t)fmaxf(acc, 0.f);
        }
    }
    __syncthreads();

    // ---- enc2 via MFMA: wave wv rows [32wv,32wv+32); rows<256 -> h0(hx[0]), >=256 -> c0(cbuf) ----
    float* cbuf = (float*)&wo1l[0][0];  // fp32 [256][17]
    {
        f32x4 e[2] = {zero4, zero4};
        #pragma unroll
        for (int kk = 0; kk < 9; ++kk) {
            int ko = 32 * kk + 8 * quad;
            bf16x8 bf = *(const bf16x8*)&hx[1][l15][ko];
            #pragma unroll
            for (int m = 0; m < 2; ++m) {
                bf16x8 a = *(const bf16x8*)&w2e[(size_t)(32 * wv + 16 * m + l15) * KEXT + ko];
                e[m] = MFMA16(a, bf, e[m]);
            }
        }
        #pragma unroll
        for (int m = 0; m < 2; ++m) {
            int row = 32 * wv + 16 * m + 4 * quad;
            if (row < 256) {  // h0
                *(unsigned*)&hx[0][l15][row]     = pk2(fmaxf(e[m][0], 0.f), fmaxf(e[m][1], 0.f));
                *(unsigned*)&hx[0][l15][row + 2] = pk2(fmaxf(e[m][2], 0.f), fmaxf(e[m][3], 0.f));
            } else {          // c0
                int d = row - 256;
                #pragma unroll
                for (int r = 0; r < 4; ++r)
                    cbuf[(size_t)(d + r) * 17 + l15] = fmaxf(e[m][r], 0.f);
            }
        }
    }
    __syncthreads();

    // ---- c0 -> regs: c[r] at dim 16wv+4quad+r, batch l15 ----
    f32x4 c;
    #pragma unroll
    for (int r = 0; r < 4; ++r)
        c[r] = cbuf[(size_t)(16 * wv + 4 * quad + r) * 17 + l15];
    __syncthreads();

    // ---- Wo1 -> LDS (overwrites cbuf); Wo2 -> LDS ----
    #pragma unroll
    for (int i = 0; i < 5; ++i) {
        int idx = tid + 1024 * i;
        if (idx < 128 * 36) {
            int r = idx / 36, c8 = idx - r * 36;
            *(bf16x8*)&wo1l[r][8 * c8] = *(const bf16x8*)&wall[(size_t)(1024 + r) * KEXT + 8 * c8];
        }
    }
    #pragma unroll
    for (int i = 0; i < 2; ++i) {
        int idx = tid + 1024 * i;
        int r = idx >> 7, cc = idx & 127;
        wo2l[r][cc] = wo2e[r * 128 + cc];
    }

    // streamed gate rows: fr[rt] (gate rt) at wall[(256rt + 16wv + l15)*KEXT + 8quad + 32kk]
    const bf16_t* sb = wall + (size_t)(16 * wv + l15) * KEXT + 8 * quad;

    __syncthreads();

    // ================= time loop (3 barriers/step, R7 structure) =================
    for (int t = 0; t < TSTEPS; ++t) {
        const bf16_t (*cur)[HS] = hx[t & 1];
        bf16_t (*nxt)[HS]       = hx[(t + 1) & 1];

        // -- phase 1: gates = [h|x|1] @ W^T; 4 row-tiles streamed, single-buffered --
        f32x4 acc[4];
        #pragma unroll
        for (int rt = 0; rt < 4; ++rt) acc[rt] = zero4;

        #pragma unroll
        for (int kk = 0; kk < 9; ++kk) {
            int ko = 32 * kk + 8 * quad;
            bf16x8 bf = *(const bf16x8*)&cur[l15][ko];
            bf16x8 fr[4];
            #pragma unroll
            for (int rt = 0; rt < 4; ++rt)
                fr[rt] = *(const bf16x8*)(sb + (size_t)(256 * rt) * KEXT + 32 * kk);
            #pragma unroll
            for (int rt = 0; rt < 4; ++rt)
                acc[rt] = MFMA16(fr[rt], bf, acc[rt]);
        }

        // -- phase 2: cell update (regs) + write h_{t+1} --
        {
            float hh[4];
            #pragma unroll
            for (int r = 0; r < 4; ++r) {
                float iv = acc[0][r], fv = acc[1][r];
                float gv = acc[2][r], ov = acc[3][r];
                float cc = sigm(fv) * c[r] + sigm(iv) * tanh_f(gv);
                c[r] = cc;
                hh[r] = sigm(ov) * tanh_f(cc);
            }
            int dim = 16 * wv + 4 * quad;
            *(unsigned*)&nxt[l15][dim]     = pk2(hh[0], hh[1]);
            *(unsigned*)&nxt[l15][dim + 2] = pk2(hh[2], hh[3]);
        }
        __syncthreads();   // B1: h_{t+1} complete

        // -- phase 3 (waves 0..7): z = relu(h_{t+1} @ Wo1^T + bo1); z-dims [16wv,16wv+16) --
        if (wv < 8) {
            f32x4 za = zero4;
            #pragma unroll
            for (int kk = 0; kk < 9; ++kk) {
                int ko = 32 * kk + 8 * quad;
                bf16x8 a = *(const bf16x8*)&wo1l[16 * wv + l15][ko];
                bf16x8 b = *(const bf16x8*)&nxt[l15][ko];   // stale x cols harmless: Wo1ext=0 there
                za = MFMA16(a, b, za);
            }
            int zd = 16 * wv + 4 * quad;
            *(unsigned*)&zbuf[l15][zd]     = pk2(fmaxf(za[0], 0.f), fmaxf(za[1], 0.f));
            *(unsigned*)&zbuf[l15][zd + 2] = pk2(fmaxf(za[2], 0.f), fmaxf(za[3], 0.f));
        }
        __syncthreads();   // B2: z complete

        // -- phase 4 (wave 0): y = z @ Wo2^T + bo2; emit out + x_{t+1} --
        if (wv == 0) {
            f32x4 ya = zero4;
            #pragma unroll
            for (int kk = 0; kk < 4; ++kk) {
                int ko = 32 * kk + 8 * quad;
                ya = MFMA16(*(const bf16x8*)&wo2l[l15][ko],
                            *(const bf16x8*)&zbuf[l15][ko], ya);
            }
            if (quad == 0) {
                float y0 = ya[0] + bo2[0], y1 = ya[1] + bo2[1], y2 = ya[2] + bo2[2];
                float* op = out + ((size_t)(gb + l15) * TSTEPS + t) * 3;
                op[0] = y0; op[1] = y1; op[2] = y2;
                *(unsigned*)&nxt[l15][256] = pk2(y0, y1);
                *(unsigned*)&nxt[l15][258] = pk2(y2, 1.f);  // keep ones col = 1
            }
        }
        __syncthreads();   // B3: x_{t+1} visible
    }
}

extern "C" void kernel_launch(void* const* d_in, const int* in_sizes, int n_in,
                              void* d_out, int out_size, void* d_ws, size_t ws_size,
                              hipStream_t stream)
{
    const float* meta = (const float*)d_in[0];
    const float* W1   = (const float*)d_in[2];
    const float* b1   = (const float*)d_in[3];
    const float* W2   = (const float*)d_in[4];
    const float* b2   = (const float*)d_in[5];
    const float* Wih  = (const float*)d_in[6];
    const float* Whh  = (const float*)d_in[7];
    const float* bih  = (const float*)d_in[8];
    const float* bhh  = (const float*)d_in[9];
    const float* Wo1  = (const float*)d_in[10];
    const float* bo1  = (const float*)d_in[11];
    const float* Wo2  = (const float*)d_in[12];
    const float* bo2  = (const float*)d_in[13];
    bf16_t* ws  = (bf16_t*)d_ws;
    float*  out = (float*)d_out;

    prep_kernel<<<dim3((WS_ELEMS + 255) / 256), dim3(256), 0, stream>>>(
        W2, b2, Wih, Whh, bih, bhh, Wo1, bo1, Wo2, ws);
    lstm_main<<<dim3(4096 / TILE_B), dim3(1024), 0, stream>>>(
        meta, W1, b1, bo2, ws, out);
}